// Round 4
// baseline (692.855 us; speedup 1.0000x reference)
//
#include <hip/hip_runtime.h>
#include <stdint.h>

#define KTAPS 8
#define C 32
#define CAP 4      // bucket slots per (out_row, tap); Poisson(0.5) overflow ~500 total
#define RPB 64     // rules per block (contrib)
#define ROWS_PB 8  // rows per block (reduce)

// ---------------------------------------------------------------------------
// init: out[row][c] = bias[c], counts[cell] = 0 (both poisoned 0xAA pre-call)
// ---------------------------------------------------------------------------
__global__ __launch_bounds__(256) void init_kernel(
    float* __restrict__ out, const float* __restrict__ bias,
    unsigned int* __restrict__ counts, int n_out4, int n_cells4) {
  int i = blockIdx.x * 256 + threadIdx.x;
  if (i < n_out4) ((float4*)out)[i] = ((const float4*)bias)[i & 7];
  if (i < n_cells4) ((uint4*)counts)[i] = make_uint4(0u, 0u, 0u, 0u);
}

// ---------------------------------------------------------------------------
// contrib: lane=co, 32-lane group=rule. Coalesced 128B gather -> LDS stage ->
// broadcast float4 reads -> 32 FMAs/lane vs register-held weight column ->
// 256B/wave contiguous contrib store. One slot-claim atomic per rule (lane 0),
// issued EARLY so its return latency hides behind the GEMM. Overflow -> direct
// f32 atomics on out (out already bias-initialized).
// ---------------------------------------------------------------------------
__global__ __launch_bounds__(256) void contrib_kernel(
    const float* __restrict__ in, const float* __restrict__ w,
    const int* __restrict__ rules_in, const int* __restrict__ rules_out,
    float* __restrict__ out, unsigned int* __restrict__ counts,
    unsigned int* __restrict__ bidx, float* __restrict__ contrib, int R) {
  const int k  = blockIdx.y;
  const int g  = threadIdx.x >> 5;   // group (rule slot in strip), 0..7
  const int co = threadIdx.x & 31;   // output channel = lane in group
  __shared__ float sA[2][8 * C];

  // column co of W[k] into 32 VGPRs (k block-uniform, loads coalesced per ci)
  const float* wk = w + k * (C * C);
  float wreg[C];
#pragma unroll
  for (int ci = 0; ci < C; ++ci) wreg[ci] = wk[ci * C + co];

  const int kR   = k * R;
  const int base = blockIdx.x * RPB;

  for (int s = 0; s < RPB / 8; ++s) {
    const int r = base + s * 8 + g;
    const bool act = (r < R);
    int ri = 0, ro = 0;
    float av = 0.f;
    unsigned slot0 = 0u;
    if (act) {
      ri = rules_in[kR + r];   // same addr across group -> broadcast
      ro = rules_out[kR + r];
      if (co == 0)             // early claim; return used after GEMM
        slot0 = atomicAdd(counts + (size_t)(unsigned)ro * KTAPS + k, 1u);
      av = in[(size_t)ri * C + co];          // coalesced: 2 lines per rule
      sA[s & 1][g * C + co] = av;
    }
    __syncthreads();
    if (act) {
      const float4* arow = (const float4*)(&sA[s & 1][g * C]);
      float acc0 = 0.f, acc1 = 0.f;
#pragma unroll
      for (int q = 0; q < 8; q += 2) {       // broadcast b128 reads, free
        float4 a0 = arow[q];
        float4 a1 = arow[q + 1];
        acc0 = fmaf(a0.x, wreg[4 * q + 0], acc0);
        acc0 = fmaf(a0.y, wreg[4 * q + 1], acc0);
        acc0 = fmaf(a0.z, wreg[4 * q + 2], acc0);
        acc0 = fmaf(a0.w, wreg[4 * q + 3], acc0);
        acc1 = fmaf(a1.x, wreg[4 * q + 4], acc1);
        acc1 = fmaf(a1.y, wreg[4 * q + 5], acc1);
        acc1 = fmaf(a1.z, wreg[4 * q + 6], acc1);
        acc1 = fmaf(a1.w, wreg[4 * q + 7], acc1);
      }
      const float acc = acc0 + acc1;
      const int t = kR + r;
      contrib[(size_t)t * C + co] = acc;     // 256B contiguous per wave

      const unsigned slot = (unsigned)__shfl((int)slot0, 0, 32);
      if (slot < (unsigned)CAP) {
        if (co == 0)
          bidx[((size_t)(unsigned)ro * KTAPS + k) * CAP + slot] = (unsigned)t;
      } else {
        unsafeAtomicAdd(out + (size_t)ro * C + co, acc);  // rare
      }
    }
  }
}

// ---------------------------------------------------------------------------
// reduce: lane=co, group=output row. Coalesced 128B read of the row's 32 slot
// indices, ballot -> group-uniform mask walk; each contribution is one
// coalesced 128B read + 1 add per lane. RMW of out (bias + overflow already
// there). Row written exactly once.
// ---------------------------------------------------------------------------
__global__ __launch_bounds__(256) void reduce_kernel(
    const unsigned int* __restrict__ counts,
    const unsigned int* __restrict__ bidx,
    const float* __restrict__ contrib,
    float* __restrict__ out, int n_out) {
  const int g   = threadIdx.x >> 5;
  const int co  = threadIdx.x & 31;
  const int row = blockIdx.x * ROWS_PB + g;
  if (row >= n_out) return;

  // slot co of this row: tap = co>>2, entry = co&3
  unsigned bval = bidx[(size_t)row * (KTAPS * CAP) + co];   // coalesced 128B
  unsigned cnt  = counts[(size_t)row * KTAPS + (co >> 2)];
  if (cnt > (unsigned)CAP) cnt = (unsigned)CAP;
  const bool valid = (unsigned)(co & 3) < cnt;

  unsigned long long bal = __ballot(valid);
  unsigned mask = (threadIdx.x & 32) ? (unsigned)(bal >> 32) : (unsigned)bal;

  float acc = out[(size_t)row * C + co];     // bias + overflow atomics
  while (mask) {
    const int j = __ffs(mask) - 1;           // group-uniform
    mask &= mask - 1;
    const unsigned t = (unsigned)__shfl((int)bval, j, 32);
    acc += contrib[(size_t)t * C + co];      // coalesced 128B per row
  }
  out[(size_t)row * C + co] = acc;
}

// ---------------------------------------------------------------------------
// Fallback (no workspace): round-1 direct-atomic path.
// ---------------------------------------------------------------------------
__global__ __launch_bounds__(256) void bias_init_kernel(
    float* __restrict__ out, const float* __restrict__ bias, int n4) {
  int idx = blockIdx.x * 256 + threadIdx.x;
  if (idx >= n4) return;
  ((float4*)out)[idx] = ((const float4*)bias)[idx & 7];
}

__global__ __launch_bounds__(256) void scatter_gemm_kernel(
    const float* __restrict__ in, const float* __restrict__ w,
    const int* __restrict__ rules_in, const int* __restrict__ rules_out,
    float* __restrict__ out, int R) {
  const int k = blockIdx.y;
  const int r = blockIdx.x * 256 + threadIdx.x;
  if (r >= R) return;
  const int ri = rules_in[k * R + r];
  const int ro = rules_out[k * R + r];
  const float4* rowp = (const float4*)(in + (size_t)ri * C);
  float a[C];
#pragma unroll
  for (int j = 0; j < 8; ++j) {
    float4 v = rowp[j];
    a[4 * j + 0] = v.x; a[4 * j + 1] = v.y;
    a[4 * j + 2] = v.z; a[4 * j + 3] = v.w;
  }
  const float* wk = w + k * (C * C);
  float acc[C];
#pragma unroll
  for (int co = 0; co < C; ++co) acc[co] = a[0] * wk[co];
#pragma unroll
  for (int ci = 1; ci < C; ++ci)
#pragma unroll
    for (int co = 0; co < C; ++co)
      acc[co] = fmaf(a[ci], wk[ci * C + co], acc[co]);
  float* op = out + (size_t)ro * C;
#pragma unroll
  for (int co = 0; co < C; ++co) unsafeAtomicAdd(op + co, acc[co]);
}

extern "C" void kernel_launch(void* const* d_in, const int* in_sizes, int n_in,
                              void* d_out, int out_size, void* d_ws, size_t ws_size,
                              hipStream_t stream) {
  const float* in_features = (const float*)d_in[0];
  const float* weight      = (const float*)d_in[1];
  const float* bias        = (const float*)d_in[2];
  const int*   rules_in    = (const int*)d_in[3];
  const int*   rules_out   = (const int*)d_in[4];

  const int R     = in_sizes[3] / KTAPS;   // 200000
  const int n_out = out_size / C;          // 400000
  float* out = (float*)d_out;

  const size_t n_cells   = (size_t)n_out * KTAPS;                 // 3.2M
  const size_t counts_b  = n_cells * sizeof(unsigned int);        // 12.8 MB
  const size_t bidx_b    = n_cells * CAP * sizeof(unsigned int);  // 51.2 MB
  const size_t n_rules   = (size_t)KTAPS * R;                     // 1.6M
  const size_t contrib_b = n_rules * C * sizeof(float);           // 204.8 MB

  const int n_out4   = out_size / 4;
  const int n_cells4 = (int)(n_cells / 4);
  const int init_n   = n_out4 > n_cells4 ? n_out4 : n_cells4;

  if (ws_size >= counts_b + bidx_b + contrib_b) {
    unsigned int* counts  = (unsigned int*)d_ws;
    unsigned int* bidx    = (unsigned int*)((char*)d_ws + counts_b);
    float*        contrib = (float*)((char*)d_ws + counts_b + bidx_b);

    init_kernel<<<(init_n + 255) / 256, 256, 0, stream>>>(out, bias, counts,
                                                          n_out4, n_cells4);
    dim3 gridB((R + RPB - 1) / RPB, KTAPS);
    contrib_kernel<<<gridB, 256, 0, stream>>>(in_features, weight, rules_in,
                                              rules_out, out, counts, bidx,
                                              contrib, R);
    reduce_kernel<<<(n_out + ROWS_PB - 1) / ROWS_PB, 256, 0, stream>>>(
        counts, bidx, contrib, out, n_out);
  } else {
    bias_init_kernel<<<(n_out4 + 255) / 256, 256, 0, stream>>>(out, bias, n_out4);
    dim3 grid((R + 255) / 256, KTAPS);
    scatter_gemm_kernel<<<grid, 256, 0, stream>>>(in_features, weight, rules_in,
                                                  rules_out, out, R);
  }
}

// Round 5
// 643.060 us; speedup vs baseline: 1.0774x; 1.0774x over previous
//
#include <hip/hip_runtime.h>
#include <stdint.h>

#define KTAPS 8
#define C 32
#define CAPR 16      // per-row bucket capacity (lambda=4; P(count>16)~1.5e-5)
#define RPB 64       // rules per block in contrib (8 groups x 8 strips)
#define ROWS_PB 8    // rows per block in reduce
#define OMAX 8192    // overflow list capacity (expected ~7 entries)

// ---------------------------------------------------------------------------
// init: zero counts region only (n_out row-counters + ocount + pad).
// out needs no init: reduce writes every row (bias added in-register).
// ---------------------------------------------------------------------------
__global__ __launch_bounds__(256) void init_kernel(
    unsigned int* __restrict__ counts, int n_cnt4) {
  int i = blockIdx.x * 256 + threadIdx.x;
  if (i < n_cnt4) ((uint4*)counts)[i] = make_uint4(0u, 0u, 0u, 0u);
}

// ---------------------------------------------------------------------------
// contrib: lane=co, 32-lane group=rule, NO BARRIER (sA slice written+read by
// the same wave; same-wave DS ops are lgkmcnt-ordered). Full 8-strip unroll:
// rules prefetched (one lane-indexed load + shfl), so 8 gathers + 8 early
// slot-claim atomics are in flight per wave. Weight column in 32 VGPRs.
// Coalesced gather (2 lines/rule), contiguous 256B/wave contrib store.
// Overflow (slot>=CAPR) appends {ro,t} to a tiny list for post-reduce fixup.
// ---------------------------------------------------------------------------
__global__ __launch_bounds__(256) void contrib_kernel(
    const float* __restrict__ in, const float* __restrict__ w,
    const int* __restrict__ rules_in, const int* __restrict__ rules_out,
    unsigned int* __restrict__ counts, unsigned int* __restrict__ bidx,
    uint2* __restrict__ oflow, unsigned int* __restrict__ ocount,
    float* __restrict__ contrib, int R) {
  const int k  = blockIdx.y;
  const int g  = threadIdx.x >> 5;   // group 0..7
  const int co = threadIdx.x & 31;   // output channel = lane in group
  __shared__ float sA[8][8][C];      // [strip][group][ci] — per-group slices

  // column co of W[k] into 32 VGPRs (k block-uniform; each load coalesced)
  const float* wk = w + k * (C * C);
  float wreg[C];
#pragma unroll
  for (int ci = 0; ci < C; ++ci) wreg[ci] = wk[ci * C + co];

  const int kR   = k * R;
  const int base = blockIdx.x * RPB;

  // prefetch this group's 8 rule pairs: lane s (s<8) holds rule (base+s*8+g)
  int my_ri = 0, my_ro = 0;
  if (co < 8) {
    const int rr = base + co * 8 + g;
    if (rr < R) {
      my_ri = rules_in[kR + rr];
      my_ro = rules_out[kR + rr];
    }
  }

#pragma unroll
  for (int s = 0; s < 8; ++s) {
    const int r = base + s * 8 + g;
    if (r < R) {
      const int ri = __shfl(my_ri, s, 32);
      const int ro = __shfl(my_ro, s, 32);

      unsigned int slot0 = 0u;
      if (co == 0)  // early claim; return consumed after the GEMM
        slot0 = atomicAdd(counts + (unsigned int)ro, 1u);

      const float av = in[(size_t)ri * C + co];   // coalesced: 2 lines/rule
      sA[s][g][co] = av;                          // same-wave slice, no barrier

      const float4* arow = (const float4*)sA[s][g];
      float acc0 = 0.f, acc1 = 0.f;
#pragma unroll
      for (int q = 0; q < 8; q += 2) {            // broadcast b128 reads
        float4 a0 = arow[q];
        float4 a1 = arow[q + 1];
        acc0 = fmaf(a0.x, wreg[4 * q + 0], acc0);
        acc0 = fmaf(a0.y, wreg[4 * q + 1], acc0);
        acc0 = fmaf(a0.z, wreg[4 * q + 2], acc0);
        acc0 = fmaf(a0.w, wreg[4 * q + 3], acc0);
        acc1 = fmaf(a1.x, wreg[4 * q + 4], acc1);
        acc1 = fmaf(a1.y, wreg[4 * q + 5], acc1);
        acc1 = fmaf(a1.z, wreg[4 * q + 6], acc1);
        acc1 = fmaf(a1.w, wreg[4 * q + 7], acc1);
      }
      const float acc = acc0 + acc1;

      const unsigned int t = (unsigned int)(kR + r);
      contrib[(size_t)t * C + co] = acc;          // 256B contiguous per wave

      const unsigned int slot = (unsigned int)__shfl((int)slot0, 0, 32);
      if (slot < (unsigned int)CAPR) {
        if (co == 0) bidx[(size_t)(unsigned int)ro * CAPR + slot] = t;
      } else if (co == 0) {
        unsigned int j = atomicAdd(ocount, 1u);
        if (j < (unsigned int)OMAX) oflow[j] = make_uint2((unsigned int)ro, t);
      }
    }
  }
}

// ---------------------------------------------------------------------------
// reduce: lane=co, group=row. Valid bucket slots are exactly 0..cnt-1 (dense
// atomic claims) -> no ballot walk; 8 predicated INDEPENDENT loads give MLP.
// bias added in-register; row written exactly once (pure store, no RMW).
// ---------------------------------------------------------------------------
__global__ __launch_bounds__(256) void reduce_kernel(
    const unsigned int* __restrict__ counts,
    const unsigned int* __restrict__ bidx,
    const float* __restrict__ contrib, const float* __restrict__ bias,
    float* __restrict__ out, int n_out) {
  const int g   = threadIdx.x >> 5;
  const int co  = threadIdx.x & 31;
  const int row = blockIdx.x * ROWS_PB + g;
  if (row >= n_out) return;

  unsigned int cnt = counts[row];                 // group-uniform broadcast
  if (cnt > (unsigned int)CAPR) cnt = (unsigned int)CAPR;

  unsigned int bval = 0u;
  if (co < CAPR) bval = bidx[(size_t)row * CAPR + co];  // coalesced 64B/group

  float acc = bias[co];
  float v[8];
#pragma unroll
  for (int j = 0; j < 8; ++j) {                   // independent masked loads
    const unsigned int tj = (unsigned int)__shfl((int)bval, j, 32);
    v[j] = 0.f;
    if (j < (int)cnt) v[j] = contrib[(size_t)tj * C + co];
  }
#pragma unroll
  for (int j = 0; j < 8; ++j) acc += v[j];
  for (int j = 8; j < (int)cnt; ++j) {            // rare tail (cnt>8)
    const unsigned int tj = (unsigned int)__shfl((int)bval, j, 32);
    acc += contrib[(size_t)tj * C + co];
  }

  out[(size_t)row * C + co] = acc;
}

// ---------------------------------------------------------------------------
// overflow fixup: runs AFTER reduce; adds the rare (slot>=CAPR) contributions
// with device-scope f32 atomics. Grid-stride over the list; ~0-10 entries.
// ---------------------------------------------------------------------------
__global__ __launch_bounds__(256) void oflow_kernel(
    const uint2* __restrict__ oflow, const unsigned int* __restrict__ ocount,
    const float* __restrict__ contrib, float* __restrict__ out) {
  const int g  = threadIdx.x >> 5;
  const int co = threadIdx.x & 31;
  unsigned int n = *ocount;
  if (n > (unsigned int)OMAX) n = (unsigned int)OMAX;
  for (unsigned int e = blockIdx.x * 8 + g; e < n; e += gridDim.x * 8) {
    const uint2 ent = oflow[e];
    unsafeAtomicAdd(out + (size_t)ent.x * C + co,
                    contrib[(size_t)ent.y * C + co]);
  }
}

// ---------------------------------------------------------------------------
// Fallback (workspace too small): round-1 direct-atomic path.
// ---------------------------------------------------------------------------
__global__ __launch_bounds__(256) void bias_init_kernel(
    float* __restrict__ out, const float* __restrict__ bias, int n4) {
  int idx = blockIdx.x * 256 + threadIdx.x;
  if (idx >= n4) return;
  ((float4*)out)[idx] = ((const float4*)bias)[idx & 7];
}

__global__ __launch_bounds__(256) void scatter_gemm_kernel(
    const float* __restrict__ in, const float* __restrict__ w,
    const int* __restrict__ rules_in, const int* __restrict__ rules_out,
    float* __restrict__ out, int R) {
  const int k = blockIdx.y;
  const int r = blockIdx.x * 256 + threadIdx.x;
  if (r >= R) return;
  const int ri = rules_in[k * R + r];
  const int ro = rules_out[k * R + r];
  const float4* rowp = (const float4*)(in + (size_t)ri * C);
  float a[C];
#pragma unroll
  for (int j = 0; j < 8; ++j) {
    float4 vv = rowp[j];
    a[4 * j + 0] = vv.x; a[4 * j + 1] = vv.y;
    a[4 * j + 2] = vv.z; a[4 * j + 3] = vv.w;
  }
  const float* wk = w + k * (C * C);
  float acc[C];
#pragma unroll
  for (int co = 0; co < C; ++co) acc[co] = a[0] * wk[co];
#pragma unroll
  for (int ci = 1; ci < C; ++ci)
#pragma unroll
    for (int co = 0; co < C; ++co)
      acc[co] = fmaf(a[ci], wk[ci * C + co], acc[co]);
  float* op = out + (size_t)ro * C;
#pragma unroll
  for (int co = 0; co < C; ++co) unsafeAtomicAdd(op + co, acc[co]);
}

extern "C" void kernel_launch(void* const* d_in, const int* in_sizes, int n_in,
                              void* d_out, int out_size, void* d_ws, size_t ws_size,
                              hipStream_t stream) {
  const float* in_features = (const float*)d_in[0];
  const float* weight      = (const float*)d_in[1];
  const float* bias        = (const float*)d_in[2];
  const int*   rules_in    = (const int*)d_in[3];
  const int*   rules_out   = (const int*)d_in[4];

  const int R     = in_sizes[3] / KTAPS;   // 200000
  const int n_out = out_size / C;          // 400000
  float* out = (float*)d_out;

  // workspace layout (16B-aligned sections)
  const size_t n_cnt     = ((size_t)n_out + 16) & ~(size_t)3;  // counts + ocount + pad
  const size_t counts_b  = n_cnt * sizeof(unsigned int);             // ~1.6 MB
  const size_t bidx_b    = (size_t)n_out * CAPR * sizeof(unsigned int); // 25.6 MB
  const size_t oflow_b   = (size_t)OMAX * sizeof(uint2);             // 64 KB
  const size_t n_rules   = (size_t)KTAPS * R;                        // 1.6M
  const size_t contrib_b = n_rules * C * sizeof(float);              // 204.8 MB

  if (ws_size >= counts_b + bidx_b + oflow_b + contrib_b) {
    unsigned int* counts  = (unsigned int*)d_ws;
    unsigned int* ocount  = counts + n_out;      // one cell inside counts region
    unsigned int* bidx    = (unsigned int*)((char*)d_ws + counts_b);
    uint2*        oflow   = (uint2*)((char*)d_ws + counts_b + bidx_b);
    float*        contrib = (float*)((char*)d_ws + counts_b + bidx_b + oflow_b);

    const int n_cnt4 = (int)(n_cnt / 4);
    init_kernel<<<(n_cnt4 + 255) / 256, 256, 0, stream>>>(counts, n_cnt4);

    dim3 gridB((R + RPB - 1) / RPB, KTAPS);
    contrib_kernel<<<gridB, 256, 0, stream>>>(in_features, weight, rules_in,
                                              rules_out, counts, bidx, oflow,
                                              ocount, contrib, R);

    reduce_kernel<<<(n_out + ROWS_PB - 1) / ROWS_PB, 256, 0, stream>>>(
        counts, bidx, contrib, bias, out, n_out);

    oflow_kernel<<<32, 256, 0, stream>>>(oflow, ocount, contrib, out);
  } else {
    const int n_out4 = out_size / 4;
    bias_init_kernel<<<(n_out4 + 255) / 256, 256, 0, stream>>>(out, bias, n_out4);
    dim3 grid((R + 255) / 256, KTAPS);
    scatter_gemm_kernel<<<grid, 256, 0, stream>>>(in_features, weight, rules_in,
                                                  rules_out, out, R);
  }
}

// Round 6
// 470.379 us; speedup vs baseline: 1.4730x; 1.3671x over previous
//
#include <hip/hip_runtime.h>
#include <stdint.h>

#define KTAPS 8
#define C 32
#define CAPR 16      // per-row bucket capacity (lambda=4; P(cnt>16)~6e-7/row)
#define OMAX 8192    // overflow list capacity (expected <1 entry)

// ---------------------------------------------------------------------------
// init: zero counts (n_out row-counters + ocount + pad). out needs no init:
// reduce writes every row exactly once (bias added in-register).
// ---------------------------------------------------------------------------
__global__ __launch_bounds__(256) void init_kernel(
    unsigned int* __restrict__ counts, int n_cnt4) {
  int i = blockIdx.x * 256 + threadIdx.x;
  if (i < n_cnt4) ((uint4*)counts)[i] = make_uint4(0u, 0u, 0u, 0u);
}

// ---------------------------------------------------------------------------
// contrib: thread-per-rule (round-3 shape — 8 independent float4 gathers =
// 8KB/wave in flight, the proven-fastest MLP). k = blockIdx.y is block-uniform
// -> W[k] scalar-loaded, GEMM is pure v_fmac v,s,v. Slot-claim atomic issued
// AFTER the gathers (so the GEMM's vmcnt wait leaves it in flight) and its
// return consumed only after ~2048 cycles of FMA. Contrib stream written at
// deterministic t = k*R + r; bucket holds only t.
// ---------------------------------------------------------------------------
__global__ __launch_bounds__(256) void contrib_kernel(
    const float* __restrict__ in, const float* __restrict__ w,
    const int* __restrict__ rules_in, const int* __restrict__ rules_out,
    unsigned int* __restrict__ counts, unsigned int* __restrict__ bidx,
    uint2* __restrict__ oflow, unsigned int* __restrict__ ocount,
    float* __restrict__ contrib, int R) {
  const int k = blockIdx.y;
  const int r = blockIdx.x * 256 + threadIdx.x;
  if (r >= R) return;

  const int ri = rules_in[k * R + r];
  const int ro = rules_out[k * R + r];

  // 8 independent 16B gathers — all in flight together
  const float4* rowp = (const float4*)(in + (size_t)ri * C);
  float4 av[8];
#pragma unroll
  for (int j = 0; j < 8; ++j) av[j] = rowp[j];

  // claim issued here: behind the gathers in the vmcnt FIFO, ahead of the
  // long FMA block that hides its ~700-cycle return latency
  const unsigned int slot = atomicAdd(counts + (unsigned int)ro, 1u);

  float a[C];
#pragma unroll
  for (int j = 0; j < 8; ++j) {
    a[4 * j + 0] = av[j].x; a[4 * j + 1] = av[j].y;
    a[4 * j + 2] = av[j].z; a[4 * j + 3] = av[j].w;
  }

  const float* wk = w + k * (C * C);   // block-uniform -> scalar pipe
  float acc[C];
#pragma unroll
  for (int co = 0; co < C; ++co) acc[co] = a[0] * wk[co];
#pragma unroll
  for (int ci = 1; ci < C; ++ci)
#pragma unroll
    for (int co = 0; co < C; ++co)
      acc[co] = fmaf(a[ci], wk[ci * C + co], acc[co]);

  const unsigned int t = (unsigned int)(k * R + r);
  float4* cp = (float4*)(contrib + (size_t)t * C);
#pragma unroll
  for (int j = 0; j < 8; ++j)
    cp[j] = make_float4(acc[4 * j + 0], acc[4 * j + 1],
                        acc[4 * j + 2], acc[4 * j + 3]);

  if (slot < (unsigned int)CAPR) {
    bidx[(size_t)(unsigned int)ro * CAPR + slot] = t;
  } else {
    unsigned int j = atomicAdd(ocount, 1u);
    if (j < (unsigned int)OMAX) oflow[j] = make_uint2((unsigned int)ro, t);
  }
}

// ---------------------------------------------------------------------------
// reduce: lane=co, 32-lane group = TWO rows. One coalesced 128B read covers
// both rows' buckets. All 32 contribution loads issued as independent
// clamp-to-index-0 loads (dummy slots hit the single hot contrib[0] line),
// validity applied by cndmask AFTER the load -> no branches, 8KB/wave in
// flight. bias in-register; each row written exactly once (pure store).
// ---------------------------------------------------------------------------
__global__ __launch_bounds__(256) void reduce_kernel(
    const unsigned int* __restrict__ counts,
    const unsigned int* __restrict__ bidx,
    const float* __restrict__ contrib, const float* __restrict__ bias,
    float* __restrict__ out, int n_out) {
  const int g    = threadIdx.x >> 5;
  const int lane = threadIdx.x & 31;
  const int rowA = (blockIdx.x * 8 + g) * 2;
  if (rowA >= n_out) return;
  const int rowB = rowA + 1;                    // n_out is even

  // lane<16: rowA slots 0-15; lane>=16: rowB slots 0-15 (contiguous 128B)
  const unsigned int bval = bidx[(size_t)rowA * CAPR + lane];
  unsigned int cntA = counts[rowA]; if (cntA > (unsigned int)CAPR) cntA = CAPR;
  unsigned int cntB = counts[rowB]; if (cntB > (unsigned int)CAPR) cntB = CAPR;

  float vA[CAPR], vB[CAPR];
#pragma unroll
  for (int j = 0; j < CAPR; ++j) {
    const unsigned int tA = (unsigned int)__shfl((int)bval, j, 32);
    const unsigned int sA = (j < (int)cntA) ? tA : 0u;   // safe dummy: line 0
    vA[j] = contrib[(size_t)sA * C + lane];              // coalesced 128B
  }
#pragma unroll
  for (int j = 0; j < CAPR; ++j) {
    const unsigned int tB = (unsigned int)__shfl((int)bval, CAPR + j, 32);
    const unsigned int sB = (j < (int)cntB) ? tB : 0u;
    vB[j] = contrib[(size_t)sB * C + lane];
  }

  const float b = bias[lane];
  float accA = b, accB = b;
#pragma unroll
  for (int j = 0; j < CAPR; ++j) {
    accA += (j < (int)cntA) ? vA[j] : 0.f;    // cndmask after load
    accB += (j < (int)cntB) ? vB[j] : 0.f;
  }

  out[(size_t)rowA * C + lane] = accA;
  out[(size_t)rowB * C + lane] = accB;
}

// ---------------------------------------------------------------------------
// overflow fixup: after reduce, add the rare slot>=CAPR contributions.
// ---------------------------------------------------------------------------
__global__ __launch_bounds__(256) void oflow_kernel(
    const uint2* __restrict__ oflow, const unsigned int* __restrict__ ocount,
    const float* __restrict__ contrib, float* __restrict__ out) {
  const int g  = threadIdx.x >> 5;
  const int co = threadIdx.x & 31;
  unsigned int n = *ocount;
  if (n > (unsigned int)OMAX) n = (unsigned int)OMAX;
  for (unsigned int e = blockIdx.x * 8 + g; e < n; e += gridDim.x * 8) {
    const uint2 ent = oflow[e];
    unsafeAtomicAdd(out + (size_t)ent.x * C + co,
                    contrib[(size_t)ent.y * C + co]);
  }
}

// ---------------------------------------------------------------------------
// Fallback (workspace too small): round-1 direct-atomic path.
// ---------------------------------------------------------------------------
__global__ __launch_bounds__(256) void bias_init_kernel(
    float* __restrict__ out, const float* __restrict__ bias, int n4) {
  int idx = blockIdx.x * 256 + threadIdx.x;
  if (idx >= n4) return;
  ((float4*)out)[idx] = ((const float4*)bias)[idx & 7];
}

__global__ __launch_bounds__(256) void scatter_gemm_kernel(
    const float* __restrict__ in, const float* __restrict__ w,
    const int* __restrict__ rules_in, const int* __restrict__ rules_out,
    float* __restrict__ out, int R) {
  const int k = blockIdx.y;
  const int r = blockIdx.x * 256 + threadIdx.x;
  if (r >= R) return;
  const int ri = rules_in[k * R + r];
  const int ro = rules_out[k * R + r];
  const float4* rowp = (const float4*)(in + (size_t)ri * C);
  float a[C];
#pragma unroll
  for (int j = 0; j < 8; ++j) {
    float4 vv = rowp[j];
    a[4 * j + 0] = vv.x; a[4 * j + 1] = vv.y;
    a[4 * j + 2] = vv.z; a[4 * j + 3] = vv.w;
  }
  const float* wk = w + k * (C * C);
  float acc[C];
#pragma unroll
  for (int co = 0; co < C; ++co) acc[co] = a[0] * wk[co];
#pragma unroll
  for (int ci = 1; ci < C; ++ci)
#pragma unroll
    for (int co = 0; co < C; ++co)
      acc[co] = fmaf(a[ci], wk[ci * C + co], acc[co]);
  float* op = out + (size_t)ro * C;
#pragma unroll
  for (int co = 0; co < C; ++co) unsafeAtomicAdd(op + co, acc[co]);
}

extern "C" void kernel_launch(void* const* d_in, const int* in_sizes, int n_in,
                              void* d_out, int out_size, void* d_ws, size_t ws_size,
                              hipStream_t stream) {
  const float* in_features = (const float*)d_in[0];
  const float* weight      = (const float*)d_in[1];
  const float* bias        = (const float*)d_in[2];
  const int*   rules_in    = (const int*)d_in[3];
  const int*   rules_out   = (const int*)d_in[4];

  const int R     = in_sizes[3] / KTAPS;   // 200000
  const int n_out = out_size / C;          // 400000
  float* out = (float*)d_out;

  // workspace layout (16B-aligned sections)
  const size_t n_cnt     = ((size_t)n_out + 16) & ~(size_t)3;
  const size_t counts_b  = n_cnt * sizeof(unsigned int);                // ~1.6 MB
  const size_t bidx_b    = (size_t)n_out * CAPR * sizeof(unsigned int); // 25.6 MB
  const size_t oflow_b   = (size_t)OMAX * sizeof(uint2);                // 64 KB
  const size_t n_rules   = (size_t)KTAPS * R;                           // 1.6M
  const size_t contrib_b = n_rules * C * sizeof(float);                 // 204.8 MB

  if (ws_size >= counts_b + bidx_b + oflow_b + contrib_b) {
    unsigned int* counts  = (unsigned int*)d_ws;
    unsigned int* ocount  = counts + n_out;
    unsigned int* bidx    = (unsigned int*)((char*)d_ws + counts_b);
    uint2*        oflow   = (uint2*)((char*)d_ws + counts_b + bidx_b);
    float*        contrib = (float*)((char*)d_ws + counts_b + bidx_b + oflow_b);

    const int n_cnt4 = (int)(n_cnt / 4);
    init_kernel<<<(n_cnt4 + 255) / 256, 256, 0, stream>>>(counts, n_cnt4);

    dim3 gridB((R + 255) / 256, KTAPS);
    contrib_kernel<<<gridB, 256, 0, stream>>>(in_features, weight, rules_in,
                                              rules_out, counts, bidx, oflow,
                                              ocount, contrib, R);

    const int rows_per_block = 16;   // 8 groups x 2 rows
    reduce_kernel<<<(n_out + rows_per_block - 1) / rows_per_block, 256, 0,
                    stream>>>(counts, bidx, contrib, bias, out, n_out);

    oflow_kernel<<<32, 256, 0, stream>>>(oflow, ocount, contrib, out);
  } else {
    const int n_out4 = out_size / 4;
    bias_init_kernel<<<(n_out4 + 255) / 256, 256, 0, stream>>>(out, bias, n_out4);
    dim3 grid((R + 255) / 256, KTAPS);
    scatter_gemm_kernel<<<grid, 256, 0, stream>>>(in_features, weight, rules_in,
                                                  rules_out, out, R);
  }
}